// Round 8
// baseline (206.593 us; speedup 1.0000x reference)
//
#include <hip/hip_runtime.h>
#include <math.h>
#include <stdint.h>

typedef unsigned long long u64;
typedef unsigned int u32;

#define NCLS 80
#define NA   8400
#define NB   16
#define PRE_K 1000
#define NBLK 256

// ---------------- ws layout (bytes) ----------------
// f_keys : u64   [NB][NA]       @ 0         (1,075,200)
// boxes  : float4[NB][NA]       @ 1,075,200 (2,150,400)
// labels : int   [NB][NA]       @ 3,225,600 (  537,600)
// cand   : u64   [NB][1024]     @ 3,763,200 (  131,072)
// mask   : u64   [NB][1000][16] @ 3,894,272 (2,048,000)  lower-tri words only
// sem    : u32   [64]           @ 5,942,272 (zeroed via hipMemsetAsync each launch)

// Device-scope grid barrier. Safe: 256 blocks; 2 blocks/CU of this shape fit
// (64KB/160KB LDS, 16/32 waves), so all 256 are resident regardless of packing.
__device__ __forceinline__ void gbar(u32* cnt) {
    __syncthreads();
    if (threadIdx.x == 0) {
        __threadfence();                              // release published data
        u32 arrived = atomicAdd(cnt, 1u) + 1u;        // device-scope
        if (arrived < (u32)NBLK) {
            while (__hip_atomic_load(cnt, __ATOMIC_RELAXED,
                                     __HIP_MEMORY_SCOPE_AGENT) < (u32)NBLK)
                __builtin_amdgcn_s_sleep(2);
        }
        __threadfence();                              // acquire
    }
    __syncthreads();
}

// ------------------------------------------------------------------
// One persistent kernel, 4 phases, 3 grid barriers.
// R7 post-mortem: 128 blocks = half chip idle; bitonic-2048 = 66
// barrier phases; decode under-parallel. R8: 256 blocks, rank-by-count
// selection (0 barriers), float2 decode, float4-packed IoU, ping-pong
// fixpoint NMS.
// ------------------------------------------------------------------
__global__ __launch_bounds__(1024, 1) void k_fused(
    const float* __restrict__ cls0, const float* __restrict__ cls1,
    const float* __restrict__ cls2, const float* __restrict__ box0,
    const float* __restrict__ box1, const float* __restrict__ box2,
    u64* __restrict__ f_keys, float4* __restrict__ boxes,
    int* __restrict__ labels, u64* __restrict__ cand,
    u64* __restrict__ mask, u32* __restrict__ sem,
    float* __restrict__ out)
{
    __shared__ __align__(16) char shm[65536];
    int blk = blockIdx.x, tid = threadIdx.x, lane = tid & 63;

    // ================= P1: decode, float2 pairs (all 256 blocks) =================
    // 67200 pairs; 263/block; a = 2*pa for every level (boundaries even).
    {
        int pair = blk * 263 + tid;
        if (tid < 263 && pair < 67200) {
            int b = pair / 4200;
            int pa = pair - b * 4200;
            const float *clsp, *boxp;
            int Wd, s, HW, hw;
            if (pa < 3200)      { clsp = cls0; boxp = box0; Wd = 80; s = 8;  HW = 6400; hw = 2 * pa; }
            else if (pa < 4000) { clsp = cls1; boxp = box1; Wd = 40; s = 16; HW = 1600; hw = 2 * pa - 6400; }
            else                { clsp = cls2; boxp = box2; Wd = 20; s = 32; HW = 400;  hw = 2 * pa - 8000; }
            int a = 2 * pa;

            const float* cp = clsp + (size_t)b * NCLS * HW + hw;
            float2 v = *(const float2*)cp;
            float m0 = v.x, m1 = v.y;
            int lab0 = 0, lab1 = 0;
#pragma unroll 8
            for (int c = 1; c < NCLS; ++c) {
                float2 vv = *(const float2*)(cp + (size_t)c * HW);
                if (vv.x > m0) { m0 = vv.x; lab0 = c; }   // strict > : first index on ties
                if (vv.y > m1) { m1 = vv.y; lab1 = c; }
            }
            double e0 = exp(-(double)m0), e1 = exp(-(double)m1);
            float sc0 = (float)(1.0 / (1.0 + e0));
            float sc1 = (float)(1.0 / (1.0 + e1));
            float sz0 = (sc0 > 0.25f) ? sc0 : 0.0f;
            float sz1 = (sc1 > 0.25f) ? sc1 : 0.0f;
            u64* fkp = f_keys + (size_t)b * NA + a;
            fkp[0] = ((u64)__float_as_uint(sz0) << 32) | (u64)(~(u32)a);
            fkp[1] = ((u64)__float_as_uint(sz1) << 32) | (u64)(~(u32)(a + 1));

            const float* bp = boxp + (size_t)b * 4 * HW + hw;
            float fs = (float)s;
            float2 q0 = *(const float2*)(bp);
            float2 q1 = *(const float2*)(bp + HW);
            float2 q2 = *(const float2*)(bp + 2 * HW);
            float2 q3 = *(const float2*)(bp + 3 * HW);
            float d00 = q0.x * fs, d01 = q1.x * fs, d02 = q2.x * fs, d03 = q3.x * fs;
            float d10 = q0.y * fs, d11 = q1.y * fs, d12 = q2.y * fs, d13 = q3.y * fs;
            float px = (float)((hw % Wd) * s);
            float py = (float)((hw / Wd) * s);
            float px1 = px + fs;                     // exact: small ints in float
            boxes[(size_t)b * NA + a]     = make_float4(px  - d00, py - d01, px  + d02, py + d03);
            boxes[(size_t)b * NA + a + 1] = make_float4(px1 - d10, py - d11, px1 + d12, py + d13);
            int2 lt; lt.x = lab0; lt.y = lab1;
            *(int2*)(labels + (size_t)b * NA + a) = lt;
        }
    }
    gbar(&sem[0]);

    // ================= P2: exact top-1000, rank-by-count (blocks 0..15) =================
    if (blk < NB) {
        u64* sh   = (u64*)shm;              // 8192 u64 = 64 KB
        u32* H    = (u32*)sh;               // 4096 bins  -> sh[0..2047]
        u32* CS   = (u32*)(sh + 2048);      // 1024 sums  -> sh[2048..2559]
        u32* MISC = (u32*)(sh + 2560);      // [0]=total [1]=B [2]=C [3]=cnt
        u64* BUF  = sh + 4096;              // 4096 keys  -> sh[4096..8191]

        int b = blk;
        const u64* fk = f_keys + (size_t)b * NA;
        u64* cb = cand + (size_t)b * 1024;

        for (int i = tid; i < 4096; i += 1024) H[i] = 0;
        if (tid == 0) { MISC[0] = 0; MISC[1] = 0; MISC[2] = 0xFFFFFFFFu; MISC[3] = 0; }
        __syncthreads();

        // histogram on score bits: score in (0.25,1) -> bin (sb>>12)-0x3E800 in [0,4095]
        for (int i = tid; i < NA; i += 1024) {
            u32 sb = (u32)(fk[i] >> 32);
            if (sb) {
                int bin = (int)(sb >> 12) - 0x3E800;
                bin = max(0, min(bin, 4095));
                atomicAdd(&H[bin], 1u);
            }
        }
        __syncthreads();

        CS[tid] = H[4*tid] + H[4*tid+1] + H[4*tid+2] + H[4*tid+3];
        __syncthreads();

        if (tid < 64) {
            u32 g = 0;
            for (int j = 0; j < 16; ++j) g += CS[lane*16 + j];
            u32 S = g;
            for (int off = 1; off < 64; off <<= 1) {
                u32 x = __shfl_down(S, off, 64);
                if (lane + off < 64) S += x;          // suffix sum over lane chunks
            }
            if (lane == 0) MISC[0] = S;
            u32 Snext = S - g;
            if (S >= PRE_K && Snext < PRE_K) {        // unique crossing lane
                u32 accAbove = Snext;
                int tB = lane * 16;
                for (int j = 15; j >= 0; --j) {
                    u32 c4 = CS[lane*16 + j];
                    if (accAbove + c4 >= PRE_K) { tB = lane*16 + j; break; }
                    accAbove += c4;
                }
                int B = 4 * tB; u32 Cv = 0;
                for (int k2 = 3; k2 >= 0; --k2) {
                    u32 hc = H[4*tB + k2];
                    if (accAbove + hc >= PRE_K) { B = 4*tB + k2; Cv = accAbove + hc; break; }
                    accAbove += hc;
                }
                MISC[1] = (u32)B; MISC[2] = Cv;
            }
        }
        __syncthreads();
        u32 total = MISC[0], Bb = MISC[1], Cv = MISC[2];
        bool fb = (total < PRE_K) || (Cv > 4096);     // block-uniform

        if (!fb) {
            // compact survivors (>= bin B); Cv in [1000, 4096]
            for (int i = tid; i < NA; i += 1024) {
                u64 key = fk[i];
                u32 sb = (u32)(key >> 32);
                if (sb) {
                    int bin = (int)(sb >> 12) - 0x3E800;
                    bin = max(0, min(bin, 4095));
                    if ((u32)bin >= Bb) {
                        u32 p = atomicAdd(&MISC[3], 1u);
                        BUF[p] = key;
                    }
                }
            }
            __syncthreads();
            // exact rank by counting (keys distinct): rank = #{BUF[j] > key}.
            // j uniform across block -> LDS broadcast. Zero barriers.
            for (int s2 = tid; s2 < (int)Cv; s2 += 1024) {
                u64 key = BUF[s2];
                int rank = 0;
                for (int j = 0; j < (int)Cv; ++j) rank += (BUF[j] > key) ? 1 : 0;
                if (rank < PRE_K) cb[rank] = key;     // top-1000 exactly fills
            }
        } else {
            // -------- fallback: exact full sort (any input) --------
            __syncthreads();
            for (int i = tid; i < 8192; i += 1024) sh[i] = fk[i];
            __syncthreads();
            for (int k = 2; k <= 8192; k <<= 1) {
                for (int j = k >> 1; j > 0; j >>= 1) {
                    for (int t = tid; t < 4096; t += 1024) {
                        int i = ((t & ~(j - 1)) << 1) | (t & (j - 1));
                        int l = i | j;
                        u64 x = sh[i], y = sh[l];
                        bool sw = ((i & k) == 0) ? (x < y) : (x > y);
                        if (sw) { sh[i] = y; sh[l] = x; }
                    }
                    __syncthreads();
                }
            }
            if (tid < 256) sh[7936 + tid] = (tid < 208) ? fk[8192 + tid] : 0ull;
            __syncthreads();
            for (int k = 2; k <= 256; k <<= 1) {
                for (int j = k >> 1; j > 0; j >>= 1) {
                    for (int t = tid; t < 128; t += 1024) {
                        int i = ((t & ~(j - 1)) << 1) | (t & (j - 1));
                        int l = i | j;
                        u64 x = sh[7936 + i], y = sh[7936 + l];
                        bool sw = ((i & k) == 0) ? (x < y) : (x > y);
                        if (sw) { sh[7936 + i] = y; sh[7936 + l] = x; }
                    }
                    __syncthreads();
                }
            }
            if (tid < 1000) {
                u64 x = sh[tid];
                int lo = 0, hi = 256;
                while (lo < hi) { int mid = (lo + hi) >> 1; if (sh[7936 + mid] > x) lo = mid + 1; else hi = mid; }
                int r = tid + lo;
                if (r < PRE_K) cb[r] = x;
            }
            if (tid < 256) {
                u64 x = sh[7936 + tid];
                int lo = 0, hi = 1024;
                while (lo < hi) { int mid = (lo + hi) >> 1; if (sh[mid] > x) lo = mid + 1; else hi = mid; }
                int r = tid + lo;
                if (r < PRE_K) cb[r] = x;
            }
        }
    }
    gbar(&sem[4]);

    // ================= P3: IoU lower-tri bitmask (16 chunks x 16 batches) =================
    {
        float4* sbox = (float4*)shm;                 // 1000 x 16 B
        float*  sar  = (float*)(shm + 16000);        // 1000 x 4 B
        int b = blk & 15, chunk = blk >> 4;
        const u64* cb = cand + (size_t)b * 1024;

        if (tid < PRE_K) {
            u64 key = cb[tid];
            u32 a = ~(u32)key;
            float4 bx = boxes[(size_t)b * NA + a];
            float off = (float)labels[(size_t)b * NA + a] * 8192.0f;  // exact mult
            float x1 = bx.x + off, y1 = bx.y + off, x2 = bx.z + off, y2 = bx.w + off;
            sbox[tid] = make_float4(x1, y1, x2, y2);
            float w = fmaxf(__fsub_rn(x2, x1), 0.0f);
            float h = fmaxf(__fsub_rn(y2, y1), 0.0f);
            sar[tid] = __fmul_rn(w, h);
        }
        __syncthreads();

        if (tid < 1008) {
            int jw = tid / 63, il = tid - jw * 63;
            int i = chunk * 63 + il;
            if (i < PRE_K && jw <= (i >> 6)) {
                float4 A = sbox[i];
                float aar = sar[i];
                int jmax = min(64, PRE_K - jw * 64);
                if (jw == (i >> 6)) jmax = min(jmax, i & 63);  // only j<i bits used by P4
                const float4* bj = sbox + jw * 64;
                const float*  aj = sar  + jw * 64;
                u64 bits = 0;
                for (int jj = 0; jj < jmax; ++jj) {
                    float4 Bx = bj[jj];                        // ds_read_b128 broadcast
                    float sab = aj[jj];
                    float lx = fmaxf(A.x, Bx.x), ly = fmaxf(A.y, Bx.y);
                    float rx = fminf(A.z, Bx.z), ry = fminf(A.w, Bx.w);
                    float ww = fmaxf(__fsub_rn(rx, lx), 0.0f);
                    float hh = fmaxf(__fsub_rn(ry, ly), 0.0f);
                    float inter = __fmul_rn(ww, hh);
                    float uni = __fsub_rn(__fadd_rn(aar, sab), inter);
                    float den = fmaxf(uni, 1e-6f);
                    float iou = inter / den;
                    if (iou > 0.65f) bits |= (1ull << jj);
                }
                mask[((size_t)b * PRE_K + i) * 16 + jw] = bits;
            }
        }
    }
    gbar(&sem[8]);

    // ================= P4: fixpoint NMS + output (blocks 0..15) =================
    if (blk < NB) {
        u64* Ksh  = (u64*)shm;                       // [2][16] ping-pong
        int* chgA = (int*)(shm + 256);               // 32 flags
        int b = blk, wv = tid >> 6;
        const u64* cb = cand + (size_t)b * 1024;
        const u64* mb = mask + (size_t)b * PRE_K * 16;

        bool inr = tid < PRE_K;
        u64 key = inr ? cb[tid] : 0ull;
        bool valid = inr && ((u32)(key >> 32) != 0u);   // score>0.25 iff bits nonzero

        u64 low = (1ull << (tid & 63)) - 1ull;          // lane 0 -> 0

        // row i, pre-masked to j<i; only words k<=wv were written by P3
        u64 rowm[16];
#pragma unroll
        for (int k = 0; k < 16; ++k) {
            u64 lt = (k < wv) ? ~0ull : ((k == wv) ? low : 0ull);
            u64 r = (inr && k <= wv) ? mb[(size_t)tid * 16 + k] : 0ull;
            rowm[k] = r & lt;
        }

        u64 v0 = __ballot(valid);                       // K^0 = valid
        if (lane == 0) Ksh[wv] = v0;
        if (tid < 32) chgA[tid] = 0;
        __syncthreads();

        int fin = 0;
        for (int it = 0; it < PRE_K + 2; ++it) {
            int p = it & 1;
            const u64* Kc = Ksh + p * 16;
            u64 kold = Kc[wv];
            u64 acc = 0;
#pragma unroll
            for (int k = 0; k < 16; ++k) acc |= rowm[k] & Kc[k];
            bool kept = valid && (acc == 0ull);
            u64 nk = __ballot(kept);
            if (lane == 0) {
                Ksh[(p ^ 1) * 16 + wv] = nk;
                if (nk != kold) chgA[it & 31] = 1;
            }
            __syncthreads();                            // one barrier per iteration
            fin = p ^ 1;
            if (chgA[it & 31] == 0) break;              // fixpoint certified
            if ((it & 31) == 31) {                      // recycle flag slots (rare)
                __syncthreads();
                if (tid < 32) chgA[tid] = 0;
                __syncthreads();
            }
        }
        const u64* Kf = Ksh + fin * 16;

        // epilogue: rank kept (by index) then zero-score backfill (by index)
        int pc = 0, Kt = 0;
#pragma unroll
        for (int k = 0; k < 16; ++k) {
            u64 kk = Kf[k];
            u64 lt = (k < wv) ? ~0ull : ((k == wv) ? low : 0ull);
            pc += __popcll(kk & lt);
            Kt += __popcll(kk);
        }
        if (inr) {
            bool kept = (Kf[wv] >> (tid & 63)) & 1ull;
            int row = kept ? pc : (Kt + (tid - pc));
            if (row < 100) {
                u32 a = ~(u32)key;
                float4 bx = boxes[(size_t)b * NA + a];
                int lab = labels[(size_t)b * NA + a];
                float fsc = kept ? __uint_as_float((u32)(key >> 32)) : 0.0f;
                float* dr = out + (size_t)(b * 100 + row) * 5;
                dr[0] = bx.x; dr[1] = bx.y; dr[2] = bx.z; dr[3] = bx.w; dr[4] = fsc;
                out[(size_t)NB * 100 * 5 + b * 100 + row] = (float)lab;
            }
        }
    }
}

extern "C" void kernel_launch(void* const* d_in, const int* in_sizes, int n_in,
                              void* d_out, int out_size, void* d_ws, size_t ws_size,
                              hipStream_t stream) {
    const float* cls0 = (const float*)d_in[0];
    const float* cls1 = (const float*)d_in[1];
    const float* cls2 = (const float*)d_in[2];
    const float* box0 = (const float*)d_in[3];
    const float* box1 = (const float*)d_in[4];
    const float* box2 = (const float*)d_in[5];
    float* out = (float*)d_out;

    char* w = (char*)d_ws;
    u64*    f_keys = (u64*)(w);
    float4* boxes  = (float4*)(w + 1075200);
    int*    labels = (int*)(w + 3225600);
    u64*    cand   = (u64*)(w + 3763200);
    u64*    mask   = (u64*)(w + 3894272);
    u32*    sem    = (u32*)(w + 5942272);

    // semaphores are 0xAA-poisoned before every launch -> zero them (captured)
    hipMemsetAsync(sem, 0, 256, stream);

    k_fused<<<NBLK, 1024, 0, stream>>>(cls0, cls1, cls2, box0, box1, box2,
                                       f_keys, boxes, labels, cand, mask, sem, out);
}

// Round 9
// 170.571 us; speedup vs baseline: 1.2112x; 1.2112x over previous
//
#include <hip/hip_runtime.h>
#include <math.h>
#include <stdint.h>

typedef unsigned long long u64;
typedef unsigned int u32;

#define NCLS 80
#define NA   8400
#define NB   16
#define PRE_K 1000
#define NBLK 256
#define AB   525      // anchors per block in P1 (16 blocks x 525 = 8400)

// ---------------- ws layout (bytes) ----------------
// f_keys : u64   [NB][NA]       @ 0         (1,075,200)
// boxes  : float4[NB][NA]       @ 1,075,200 (2,150,400)
// labels : int   [NB][NA]       @ 3,225,600 (  537,600)
// cand   : u64   [NB][1024]     @ 3,763,200 (  131,072)
// mask   : u64   [NB][1000][16] @ 3,894,272 (2,048,000)  lower-tri words only
// sem    : u32   [64]           @ 5,942,272 (256 B, memset 0 per launch)
//          [0..15]=P1 done cnt, [16..31]=A flag, [32..47]=B cnt, [48..63]=C cnt
// surv   : u64   [NB][2048]     @ 5,942,528 (  262,144)
// miscg  : u32   [NB][4]        @ 6,204,672 (      256)  total,B,Cv

// Deadlock-safe: 256 blocks; even at 1 block/CU all are resident (256 CUs).
__device__ __forceinline__ void sig(u32* s, int tid) {
    __syncthreads();
    if (tid == 0) { __threadfence(); atomicAdd(s, 1u); }
}
__device__ __forceinline__ void waitge(u32* s, u32 target, int tid) {
    if (tid == 0) {
        while (__hip_atomic_load(s, __ATOMIC_RELAXED, __HIP_MEMORY_SCOPE_AGENT) < target)
            __builtin_amdgcn_s_sleep(2);
        __threadfence();
    }
    __syncthreads();
}

// ------------------------------------------------------------------
// One persistent kernel; per-batch producer-consumer pipeline.
// R8 post-mortem: full-grid barriers x3 + under-threaded P1 + LDS-pipe-
// serialized P2 cost 137us. R9: 16-block-scope sync per batch, batches
// overlap; P1 all-proven scalar decode; P2 = histogram threshold (1 blk)
// + 16-block sliced rank-by-count; P3/P4 proven R8 bodies.
// ------------------------------------------------------------------
__global__ __launch_bounds__(1024, 1) void k_fused(
    const float* __restrict__ cls0, const float* __restrict__ cls1,
    const float* __restrict__ cls2, const float* __restrict__ box0,
    const float* __restrict__ box1, const float* __restrict__ box2,
    u64* __restrict__ f_keys, float4* __restrict__ boxes,
    int* __restrict__ labels, u64* __restrict__ cand,
    u64* __restrict__ mask, u32* __restrict__ sem,
    u64* __restrict__ surv, u32* __restrict__ miscg,
    float* __restrict__ out)
{
    __shared__ __align__(16) char shm[65536];
    __shared__ u32 s_av;
    int blk = blockIdx.x, tid = threadIdx.x, lane = tid & 63;
    int b = blk & 15, bg = blk >> 4;

    u32* semP1 = sem + 0;
    u32* semA  = sem + 16;
    u32* semB  = sem + 32;
    u32* semC  = sem + 48;
    u64* cb = cand + (size_t)b * 1024;
    u64* sv = surv + (size_t)b * 2048;

    // ================= P1: decode 525 anchors (block bg of batch b) =================
    {
        int a = bg * AB + tid;
        if (tid < AB) {
            const float* clsp; const float* boxp;
            int Wd, s, hw, HW;
            if (a < 6400)      { clsp = cls0; boxp = box0; Wd = 80; s = 8;  hw = a;        HW = 6400; }
            else if (a < 8000) { clsp = cls1; boxp = box1; Wd = 40; s = 16; hw = a - 6400; HW = 1600; }
            else               { clsp = cls2; boxp = box2; Wd = 20; s = 32; hw = a - 8000; HW = 400;  }

            const float* cp = clsp + (size_t)b * NCLS * HW + hw;
            float m = cp[0];
            int lab = 0;
#pragma unroll 8
            for (int c = 1; c < NCLS; ++c) {
                float v = cp[(size_t)c * HW];
                if (v > m) { m = v; lab = c; }   // strict > : first index on ties
            }
            double e = exp(-(double)m);
            float sc = (float)(1.0 / (1.0 + e));
            float sz = (sc > 0.25f) ? sc : 0.0f;
            f_keys[(size_t)b * NA + a] = ((u64)__float_as_uint(sz) << 32) | (u64)(~(u32)a);

            const float* bp = boxp + (size_t)b * 4 * HW + hw;
            float fs = (float)s;
            float d0 = bp[0] * fs, d1 = bp[HW] * fs, d2 = bp[2 * HW] * fs, d3 = bp[3 * HW] * fs;
            float px = (float)((hw % Wd) * s);
            float py = (float)((hw / Wd) * s);
            boxes[(size_t)b * NA + a] = make_float4(px - d0, py - d1, px + d2, py + d3);
            labels[(size_t)b * NA + a] = lab;
        }
        sig(&semP1[b], tid);
    }

    // ================= Stage A: threshold + compact (bg==0 only) =================
    if (bg == 0) {
        waitge(&semP1[b], 16, tid);
        u64* sh   = (u64*)shm;
        u32* H    = (u32*)sh;               // 4096 bins
        u32* CS   = (u32*)(sh + 2048);      // 1024 sums
        u32* MISC = (u32*)(sh + 2560);      // [0]=total [1]=B [2]=Cv [3]=cnt
        const u64* fk = f_keys + (size_t)b * NA;

        for (int i = tid; i < 4096; i += 1024) H[i] = 0;
        if (tid == 0) { MISC[0] = 0; MISC[1] = 0; MISC[2] = 0xFFFFFFFFu; MISC[3] = 0; }
        __syncthreads();

        // histogram on score bits: score in (0.25,1) -> bin (sb>>12)-0x3E800 in [0,4095]
        for (int i = tid; i < NA; i += 1024) {
            u32 sb = (u32)(fk[i] >> 32);
            if (sb) {
                int bin = (int)(sb >> 12) - 0x3E800;
                bin = max(0, min(bin, 4095));
                atomicAdd(&H[bin], 1u);
            }
        }
        __syncthreads();

        CS[tid] = H[4*tid] + H[4*tid+1] + H[4*tid+2] + H[4*tid+3];
        __syncthreads();

        if (tid < 64) {
            u32 g = 0;
            for (int j = 0; j < 16; ++j) g += CS[lane*16 + j];
            u32 S = g;
            for (int off = 1; off < 64; off <<= 1) {
                u32 x = __shfl_down(S, off, 64);
                if (lane + off < 64) S += x;          // suffix sum over lane chunks
            }
            if (lane == 0) MISC[0] = S;
            u32 Snext = S - g;
            if (S >= PRE_K && Snext < PRE_K) {        // unique crossing lane
                u32 accAbove = Snext;
                int tB = lane * 16;
                for (int j = 15; j >= 0; --j) {
                    u32 c4 = CS[lane*16 + j];
                    if (accAbove + c4 >= PRE_K) { tB = lane*16 + j; break; }
                    accAbove += c4;
                }
                int B = 4 * tB; u32 Cvl = 0;
                for (int k2 = 3; k2 >= 0; --k2) {
                    u32 hc = H[4*tB + k2];
                    if (accAbove + hc >= PRE_K) { B = 4*tB + k2; Cvl = accAbove + hc; break; }
                    accAbove += hc;
                }
                MISC[1] = (u32)B; MISC[2] = Cvl;
            }
        }
        __syncthreads();
        u32 total = MISC[0], Bb = MISC[1], Cv = MISC[2];
        bool fb = (total < PRE_K) || (Cv > 2048);     // block-uniform

        if (!fb) {
            // compact survivors (>= bin Bb) to global surv; order arbitrary
            for (int i = tid; i < NA; i += 1024) {
                u64 key = fk[i];
                u32 sb = (u32)(key >> 32);
                if (sb) {
                    int bin = (int)(sb >> 12) - 0x3E800;
                    bin = max(0, min(bin, 4095));
                    if ((u32)bin >= Bb) {
                        u32 p = atomicAdd(&MISC[3], 1u);
                        sv[p] = key;
                    }
                }
            }
            __syncthreads();
            if (tid == 0) {
                miscg[b*4 + 0] = total; miscg[b*4 + 1] = Bb; miscg[b*4 + 2] = Cv;
                __threadfence();
                atomicExch(&semA[b], 1u);
            }
        } else {
            // -------- fallback: exact full sort, writes cand directly --------
            __syncthreads();
            for (int i = tid; i < 8192; i += 1024) sh[i] = fk[i];
            __syncthreads();
            for (int k = 2; k <= 8192; k <<= 1) {
                for (int j = k >> 1; j > 0; j >>= 1) {
                    for (int t = tid; t < 4096; t += 1024) {
                        int i = ((t & ~(j - 1)) << 1) | (t & (j - 1));
                        int l = i | j;
                        u64 x = sh[i], y = sh[l];
                        bool sw = ((i & k) == 0) ? (x < y) : (x > y);
                        if (sw) { sh[i] = y; sh[l] = x; }
                    }
                    __syncthreads();
                }
            }
            if (tid < 256) sh[7936 + tid] = (tid < 208) ? fk[8192 + tid] : 0ull;
            __syncthreads();
            for (int k = 2; k <= 256; k <<= 1) {
                for (int j = k >> 1; j > 0; j >>= 1) {
                    for (int t = tid; t < 128; t += 1024) {
                        int i = ((t & ~(j - 1)) << 1) | (t & (j - 1));
                        int l = i | j;
                        u64 x = sh[7936 + i], y = sh[7936 + l];
                        bool sw = ((i & k) == 0) ? (x < y) : (x > y);
                        if (sw) { sh[7936 + i] = y; sh[7936 + l] = x; }
                    }
                    __syncthreads();
                }
            }
            if (tid < 1000) {
                u64 x = sh[tid];
                int lo = 0, hi = 256;
                while (lo < hi) { int mid = (lo + hi) >> 1; if (sh[7936 + mid] > x) lo = mid + 1; else hi = mid; }
                int r = tid + lo;
                if (r < PRE_K) cb[r] = x;
            }
            if (tid < 256) {
                u64 x = sh[7936 + tid];
                int lo = 0, hi = 1024;
                while (lo < hi) { int mid = (lo + hi) >> 1; if (sh[mid] > x) lo = mid + 1; else hi = mid; }
                int r = tid + lo;
                if (r < PRE_K) cb[r] = x;
            }
            __syncthreads();
            if (tid == 0) { __threadfence(); atomicExch(&semA[b], 2u); }
        }
    }

    // ================= Stage B: sliced rank-by-count (all 16 blocks of batch) =================
    {
        if (tid == 0) {
            u32 v;
            while ((v = __hip_atomic_load(&semA[b], __ATOMIC_RELAXED,
                                          __HIP_MEMORY_SCOPE_AGENT)) == 0u)
                __builtin_amdgcn_s_sleep(2);
            __threadfence();
            s_av = v;
        }
        __syncthreads();
        if (s_av == 1u) {
            u64* BUF   = (u64*)shm;                   // Cv <= 2048 keys (16 KB)
            u32* rankL = (u32*)(shm + 16384);         // 128 partial ranks
            u32 Cv = miscg[b*4 + 2];
            for (int i = tid; i < (int)Cv; i += 1024) BUF[i] = sv[i];
            if (tid < 128) rankL[tid] = 0;
            __syncthreads();
            int sl = tid & 127, part = tid >> 7;      // part uniform per wave -> broadcast
            int s2 = bg * 128 + sl;
            int jpb = ((int)Cv + 7) >> 3;
            int j0 = part * jpb, j1 = min((int)Cv, j0 + jpb);
            if (s2 < (int)Cv) {
                u64 key = BUF[s2];
                u32 cnt = 0;
                for (int j = j0; j < j1; ++j) cnt += (BUF[j] > key) ? 1u : 0u;
                if (cnt) atomicAdd(&rankL[sl], cnt);
            }
            __syncthreads();
            if (tid < 128) {
                int s3 = bg * 128 + tid;
                if (s3 < (int)Cv) {
                    u32 r = rankL[tid];                // exact rank (keys distinct)
                    if (r < PRE_K) cb[r] = BUF[s3];
                }
            }
        }
        sig(&semB[b], tid);
    }

    // ================= P3: IoU lower-tri bitmask (chunk bg of batch b) =================
    {
        waitge(&semB[b], 16, tid);
        float4* sbox = (float4*)shm;                 // 1000 x 16 B
        float*  sar  = (float*)(shm + 16000);        // 1000 x 4 B

        if (tid < PRE_K) {
            u64 key = cb[tid];
            u32 a = ~(u32)key;
            float4 bx = boxes[(size_t)b * NA + a];
            float off = (float)labels[(size_t)b * NA + a] * 8192.0f;  // exact mult
            float x1 = bx.x + off, y1 = bx.y + off, x2 = bx.z + off, y2 = bx.w + off;
            sbox[tid] = make_float4(x1, y1, x2, y2);
            float w = fmaxf(__fsub_rn(x2, x1), 0.0f);
            float h = fmaxf(__fsub_rn(y2, y1), 0.0f);
            sar[tid] = __fmul_rn(w, h);
        }
        __syncthreads();

        if (tid < 1008) {
            int jw = tid / 63, il = tid - jw * 63;
            int i = bg * 63 + il;
            if (i < PRE_K && jw <= (i >> 6)) {
                float4 A = sbox[i];
                float aar = sar[i];
                int jmax = min(64, PRE_K - jw * 64);
                if (jw == (i >> 6)) jmax = min(jmax, i & 63);  // only j<i bits used by P4
                const float4* bj = sbox + jw * 64;
                const float*  aj = sar  + jw * 64;
                u64 bits = 0;
                for (int jj = 0; jj < jmax; ++jj) {
                    float4 Bx = bj[jj];                        // ds_read_b128 broadcast
                    float sab = aj[jj];
                    float lx = fmaxf(A.x, Bx.x), ly = fmaxf(A.y, Bx.y);
                    float rx = fminf(A.z, Bx.z), ry = fminf(A.w, Bx.w);
                    float ww = fmaxf(__fsub_rn(rx, lx), 0.0f);
                    float hh = fmaxf(__fsub_rn(ry, ly), 0.0f);
                    float inter = __fmul_rn(ww, hh);
                    float uni = __fsub_rn(__fadd_rn(aar, sab), inter);
                    float den = fmaxf(uni, 1e-6f);
                    float iou = inter / den;
                    if (iou > 0.65f) bits |= (1ull << jj);
                }
                mask[((size_t)b * PRE_K + i) * 16 + jw] = bits;
            }
        }
        sig(&semC[b], tid);
    }

    // ================= P4: fixpoint NMS + output (bg==0 only) =================
    if (bg == 0) {
        waitge(&semC[b], 16, tid);
        u64* Ksh  = (u64*)shm;                       // [2][16] ping-pong
        int* chgA = (int*)(shm + 256);               // 32 flags
        int wv = tid >> 6;
        const u64* mb = mask + (size_t)b * PRE_K * 16;

        bool inr = tid < PRE_K;
        u64 key = inr ? cb[tid] : 0ull;
        bool valid = inr && ((u32)(key >> 32) != 0u);   // score>0.25 iff bits nonzero

        u64 low = (1ull << (tid & 63)) - 1ull;          // lane 0 -> 0

        // row i, pre-masked to j<i; only words k<=wv were written by P3
        u64 rowm[16];
#pragma unroll
        for (int k = 0; k < 16; ++k) {
            u64 lt = (k < wv) ? ~0ull : ((k == wv) ? low : 0ull);
            u64 r = (inr && k <= wv) ? mb[(size_t)tid * 16 + k] : 0ull;
            rowm[k] = r & lt;
        }

        u64 v0 = __ballot(valid);                       // K^0 = valid
        if (lane == 0) Ksh[wv] = v0;
        if (tid < 32) chgA[tid] = 0;
        __syncthreads();

        int fin = 0;
        for (int it = 0; it < PRE_K + 2; ++it) {
            int p = it & 1;
            const u64* Kc = Ksh + p * 16;
            u64 kold = Kc[wv];
            u64 acc = 0;
#pragma unroll
            for (int k = 0; k < 16; ++k) acc |= rowm[k] & Kc[k];
            bool kept = valid && (acc == 0ull);
            u64 nk = __ballot(kept);
            if (lane == 0) {
                Ksh[(p ^ 1) * 16 + wv] = nk;
                if (nk != kold) chgA[it & 31] = 1;
            }
            __syncthreads();                            // one barrier per iteration
            fin = p ^ 1;
            if (chgA[it & 31] == 0) break;              // fixpoint certified
            if ((it & 31) == 31) {                      // recycle flag slots (rare)
                __syncthreads();
                if (tid < 32) chgA[tid] = 0;
                __syncthreads();
            }
        }
        const u64* Kf = Ksh + fin * 16;

        // epilogue: rank kept (by index) then zero-score backfill (by index)
        int pc = 0, Kt = 0;
#pragma unroll
        for (int k = 0; k < 16; ++k) {
            u64 kk = Kf[k];
            u64 lt = (k < wv) ? ~0ull : ((k == wv) ? low : 0ull);
            pc += __popcll(kk & lt);
            Kt += __popcll(kk);
        }
        if (inr) {
            bool kept = (Kf[wv] >> (tid & 63)) & 1ull;
            int row = kept ? pc : (Kt + (tid - pc));
            if (row < 100) {
                u32 a = ~(u32)key;
                float4 bx = boxes[(size_t)b * NA + a];
                int lab = labels[(size_t)b * NA + a];
                float fsc = kept ? __uint_as_float((u32)(key >> 32)) : 0.0f;
                float* dr = out + (size_t)(b * 100 + row) * 5;
                dr[0] = bx.x; dr[1] = bx.y; dr[2] = bx.z; dr[3] = bx.w; dr[4] = fsc;
                out[(size_t)NB * 100 * 5 + b * 100 + row] = (float)lab;
            }
        }
    }
}

extern "C" void kernel_launch(void* const* d_in, const int* in_sizes, int n_in,
                              void* d_out, int out_size, void* d_ws, size_t ws_size,
                              hipStream_t stream) {
    const float* cls0 = (const float*)d_in[0];
    const float* cls1 = (const float*)d_in[1];
    const float* cls2 = (const float*)d_in[2];
    const float* box0 = (const float*)d_in[3];
    const float* box1 = (const float*)d_in[4];
    const float* box2 = (const float*)d_in[5];
    float* out = (float*)d_out;

    char* w = (char*)d_ws;
    u64*    f_keys = (u64*)(w);
    float4* boxes  = (float4*)(w + 1075200);
    int*    labels = (int*)(w + 3225600);
    u64*    cand   = (u64*)(w + 3763200);
    u64*    mask   = (u64*)(w + 3894272);
    u32*    sem    = (u32*)(w + 5942272);
    u64*    surv   = (u64*)(w + 5942528);
    u32*    miscg  = (u32*)(w + 6204672);

    // semaphores are 0xAA-poisoned before every launch -> zero them (captured)
    hipMemsetAsync(sem, 0, 256, stream);

    k_fused<<<NBLK, 1024, 0, stream>>>(cls0, cls1, cls2, box0, box1, box2,
                                       f_keys, boxes, labels, cand, mask, sem,
                                       surv, miscg, out);
}

// Round 10
// 140.428 us; speedup vs baseline: 1.4712x; 1.2147x over previous
//
#include <hip/hip_runtime.h>
#include <math.h>
#include <stdint.h>

typedef unsigned long long u64;
typedef unsigned int u32;

#define NCLS 80
#define NA   8400
#define NB   16
#define PRE_K 1000

// ---------------- ws layout (bytes) ----------------
// f_keys : u64   [NB][NA]       @ 0         (1,075,200)
// boxes  : float4[NB][NA]       @ 1,075,200 (2,150,400)
// labels : int   [NB][NA]       @ 3,225,600 (  537,600)
// cand   : u64   [NB][1024]     @ 3,763,200 (  131,072)
// mask   : u64   [NB][1000][16] @ 3,894,272 (2,048,000)  lower-tri words only
// sem    : u32   [64]           @ 5,942,272 (256 B, memset 0 per launch)
//          [0..15]=A flag (cand ready), [16..31]=C cnt (mask ready)

__device__ __forceinline__ void sig(u32* s, int tid) {
    __syncthreads();
    if (tid == 0) { __threadfence(); atomicAdd(s, 1u); }
}
__device__ __forceinline__ void waitge(u32* s, u32 target, int tid) {
    if (tid == 0) {
        while (__hip_atomic_load(s, __ATOMIC_RELAXED, __HIP_MEMORY_SCOPE_AGENT) < target)
            __builtin_amdgcn_s_sleep(2);
        __threadfence();
    }
    __syncthreads();
}

// ------------------------------------------------------------------
// Kernel 1: decode, float2 pairs, FULL thread utilization.
// grid (17, NB) x 256: 4352 threads/batch for 4200 pairs.
// (R8's pair math — proven absmax 0 — but without the 263/1024 waste.)
// ------------------------------------------------------------------
__global__ __launch_bounds__(256) void k_decode(
    const float* __restrict__ cls0, const float* __restrict__ cls1,
    const float* __restrict__ cls2, const float* __restrict__ box0,
    const float* __restrict__ box1, const float* __restrict__ box2,
    u64* __restrict__ f_keys, float4* __restrict__ boxes,
    int* __restrict__ labels)
{
    int pa = blockIdx.x * 256 + threadIdx.x;     // pair index in batch
    int b  = blockIdx.y;
    if (pa >= 4200) return;

    const float *clsp, *boxp;
    int Wd, s, HW, hw;
    if (pa < 3200)      { clsp = cls0; boxp = box0; Wd = 80; s = 8;  HW = 6400; hw = 2 * pa; }
    else if (pa < 4000) { clsp = cls1; boxp = box1; Wd = 40; s = 16; HW = 1600; hw = 2 * pa - 6400; }
    else                { clsp = cls2; boxp = box2; Wd = 20; s = 32; HW = 400;  hw = 2 * pa - 8000; }
    int a = 2 * pa;

    const float* cp = clsp + (size_t)b * NCLS * HW + hw;
    float2 v = *(const float2*)cp;
    float m0 = v.x, m1 = v.y;
    int lab0 = 0, lab1 = 0;
#pragma unroll 8
    for (int c = 1; c < NCLS; ++c) {
        float2 vv = *(const float2*)(cp + (size_t)c * HW);
        if (vv.x > m0) { m0 = vv.x; lab0 = c; }   // strict > : first index on ties
        if (vv.y > m1) { m1 = vv.y; lab1 = c; }
    }
    double e0 = exp(-(double)m0), e1 = exp(-(double)m1);
    float sc0 = (float)(1.0 / (1.0 + e0));
    float sc1 = (float)(1.0 / (1.0 + e1));
    float sz0 = (sc0 > 0.25f) ? sc0 : 0.0f;
    float sz1 = (sc1 > 0.25f) ? sc1 : 0.0f;
    u64* fkp = f_keys + (size_t)b * NA + a;
    fkp[0] = ((u64)__float_as_uint(sz0) << 32) | (u64)(~(u32)a);
    fkp[1] = ((u64)__float_as_uint(sz1) << 32) | (u64)(~(u32)(a + 1));

    const float* bp = boxp + (size_t)b * 4 * HW + hw;
    float fs = (float)s;
    float2 q0 = *(const float2*)(bp);
    float2 q1 = *(const float2*)(bp + HW);
    float2 q2 = *(const float2*)(bp + 2 * HW);
    float2 q3 = *(const float2*)(bp + 3 * HW);
    float px = (float)((hw % Wd) * s);
    float py = (float)((hw / Wd) * s);
    float px1 = px + fs;                          // exact: small ints in float
    boxes[(size_t)b * NA + a]     = make_float4(px  - q0.x * fs, py - q1.x * fs, px  + q2.x * fs, py + q3.x * fs);
    boxes[(size_t)b * NA + a + 1] = make_float4(px1 - q0.y * fs, py - q1.y * fs, px1 + q2.y * fs, py + q3.y * fs);
    int2 lt; lt.x = lab0; lt.y = lab1;
    *(int2*)(labels + (size_t)b * NA + a) = lt;
}

// ------------------------------------------------------------------
// Kernel 2: per-batch pipeline, 16 blocks/batch, 2 handoffs.
//  bg==0: bucket-rank selection (O(Cv), ~6 barriers, no Cv^2 loop)
//  all  : IoU lower-tri chunk bg        (R9 proven body)
//  bg==0: fixpoint NMS + output         (R9 proven body)
// Rank theory: key=(score_bits<<32)|~a; bin=(sb>>12)-0x3E800 is order-
// preserving across bins; R[bin]=suffix count => exact base rank; within
// bin compare full keys (distinct). Clamped bins stay order-safe because
// within-bin comparison is exact.
// ------------------------------------------------------------------
__global__ __launch_bounds__(1024, 1) void k_post(
    const u64* __restrict__ f_keys, const float4* __restrict__ boxes,
    const int* __restrict__ labels, u64* __restrict__ cand,
    u64* __restrict__ mask, u32* __restrict__ sem,
    float* __restrict__ out)
{
    __shared__ __align__(16) char shm[65536];
    __shared__ u32 wtot[16];
    __shared__ u32 s_total, s_B;
    int blk = blockIdx.x, tid = threadIdx.x, lane = tid & 63, wv = tid >> 6;
    int b = blk & 15, bg = blk >> 4;

    u32* semA = sem + 0;
    u32* semC = sem + 16;
    const u64* fk = f_keys + (size_t)b * NA;
    u64* cb = cand + (size_t)b * 1024;

    // ================= Selection (bg==0 only) =================
    if (bg == 0) {
        u32* R  = (u32*)shm;                 // 4096: histogram -> suffix counts
        u32* C  = (u32*)(shm + 16384);       // 4096: bucket-fill counters
        u64* BK = (u64*)(shm + 32768);       // 4096 bucket slots (32 KB)

        for (int i = tid; i < 4096; i += 1024) { R[i] = 0; C[i] = 0; }
        __syncthreads();

        // 1. histogram over score bits
        for (int i = tid; i < NA; i += 1024) {
            u32 sb = (u32)(fk[i] >> 32);
            if (sb) {
                int bin = (int)(sb >> 12) - 0x3E800;
                bin = max(0, min(bin, 4095));
                atomicAdd(&R[bin], 1u);
            }
        }
        __syncthreads();

        // 2. in-place suffix-sum: R[bin] = #keys in bins >= bin
        u32 h0 = R[4*tid], h1 = R[4*tid+1], h2 = R[4*tid+2], h3 = R[4*tid+3];
        u32 g = h0 + h1 + h2 + h3;
        u32 S = g;
#pragma unroll
        for (int off = 1; off < 64; off <<= 1) {
            u32 x = __shfl_down(S, off, 64);
            if (lane + off < 64) S += x;          // suffix-incl over lanes
        }
        if (lane == 0) wtot[wv] = S;
        __syncthreads();
        u32 wsuf = 0;
#pragma unroll
        for (int w = 0; w < 16; ++w) if (w > wv) wsuf += wtot[w];
        u32 above = (S - g) + wsuf;               // keys in bins > 4*tid+3
        u32 r3 = h3 + above, r2 = h2 + r3, r1 = h1 + r2, r0 = h0 + r1;
        R[4*tid] = r0; R[4*tid+1] = r1; R[4*tid+2] = r2; R[4*tid+3] = r3;
        if (tid == 0) s_total = 0;                // placeholder; set below by owner
        __syncthreads();
        if (tid == 0) s_total = R[0];
        __syncthreads();
        u32 total = s_total;

        // 3. threshold bin B (unique writer; B=0 if total<1000)
        if (tid == 0 && total < PRE_K) s_B = 0;
#pragma unroll
        for (int k = 0; k < 4; ++k) {
            int bin = 4*tid + k;
            u32 Rb = R[bin];
            u32 Rn = (bin < 4095) ? R[bin + 1] : 0;
            if (Rb >= PRE_K && Rn < PRE_K) s_B = (u32)bin;
        }
        __syncthreads();
        u32 B = s_B;
        u32 Cv = R[B];                            // survivors (bins >= B)

        if (Cv <= 4096) {
            // 4. bucket-place survivors at exact rank-base
            for (int i = tid; i < NA; i += 1024) {
                u64 key = fk[i];
                u32 sb = (u32)(key >> 32);
                if (sb) {
                    int bin = (int)(sb >> 12) - 0x3E800;
                    bin = max(0, min(bin, 4095));
                    if ((u32)bin >= B) {
                        u32 base = (bin < 4095) ? R[bin + 1] : 0;
                        u32 off = atomicAdd(&C[bin], 1u);
                        BK[base + off] = key;
                    }
                }
            }
            __syncthreads();
            // 5. exact rank = bucket base + #{same-bin keys greater}
            for (int s2 = tid; s2 < (int)Cv; s2 += 1024) {
                u64 key = BK[s2];
                u32 sb = (u32)(key >> 32);
                int bin = (int)(sb >> 12) - 0x3E800;
                bin = max(0, min(bin, 4095));
                u32 base = (bin < 4095) ? R[bin + 1] : 0;
                u32 n = R[bin] - base;
                u32 cnt = 0;
                for (u32 j = 0; j < n; ++j) cnt += (BK[base + j] > key) ? 1u : 0u;
                u32 rank = base + cnt;
                if (rank < PRE_K) cb[rank] = key;
            }
        } else {
            // fallback (pathological bin collisions): exact rank via global
            for (int i = tid; i < NA; i += 1024) {
                u64 key = fk[i];
                u32 sb = (u32)(key >> 32);
                if (!sb) continue;
                int bin = (int)(sb >> 12) - 0x3E800;
                bin = max(0, min(bin, 4095));
                if ((u32)bin < B) continue;
                u32 rank = 0;
                for (int j = 0; j < NA; ++j) rank += (fk[j] > key) ? 1u : 0u;
                if (rank < PRE_K) cb[rank] = key;
            }
        }
        // 6. zero-score backfill (reference: ties by index asc)
        for (int t2 = tid; (int)total + t2 < PRE_K; t2 += 1024)
            cb[total + t2] = (u64)(~(u32)t2);

        __syncthreads();
        if (tid == 0) { __threadfence(); atomicExch(&semA[b], 1u); }
    }

    // ================= IoU lower-tri bitmask (chunk bg of batch b) =================
    {
        waitge(&semA[b], 1, tid);
        float4* sbox = (float4*)shm;                 // 1000 x 16 B
        float*  sar  = (float*)(shm + 16000);        // 1000 x 4 B

        if (tid < PRE_K) {
            u64 key = cb[tid];
            u32 a = ~(u32)key;
            float4 bx = boxes[(size_t)b * NA + a];
            float off = (float)labels[(size_t)b * NA + a] * 8192.0f;  // exact mult
            float x1 = bx.x + off, y1 = bx.y + off, x2 = bx.z + off, y2 = bx.w + off;
            sbox[tid] = make_float4(x1, y1, x2, y2);
            float w = fmaxf(__fsub_rn(x2, x1), 0.0f);
            float h = fmaxf(__fsub_rn(y2, y1), 0.0f);
            sar[tid] = __fmul_rn(w, h);
        }
        __syncthreads();

        if (tid < 1008) {
            int jw = tid / 63, il = tid - jw * 63;
            int i = bg * 63 + il;
            if (i < PRE_K && jw <= (i >> 6)) {
                float4 A = sbox[i];
                float aar = sar[i];
                int jmax = min(64, PRE_K - jw * 64);
                if (jw == (i >> 6)) jmax = min(jmax, i & 63);  // only j<i bits used by NMS
                const float4* bj = sbox + jw * 64;
                const float*  aj = sar  + jw * 64;
                u64 bits = 0;
                for (int jj = 0; jj < jmax; ++jj) {
                    float4 Bx = bj[jj];                        // ds_read_b128 broadcast
                    float sab = aj[jj];
                    float lx = fmaxf(A.x, Bx.x), ly = fmaxf(A.y, Bx.y);
                    float rx = fminf(A.z, Bx.z), ry = fminf(A.w, Bx.w);
                    float ww = fmaxf(__fsub_rn(rx, lx), 0.0f);
                    float hh = fmaxf(__fsub_rn(ry, ly), 0.0f);
                    float inter = __fmul_rn(ww, hh);
                    float uni = __fsub_rn(__fadd_rn(aar, sab), inter);
                    float den = fmaxf(uni, 1e-6f);
                    float iou = inter / den;
                    if (iou > 0.65f) bits |= (1ull << jj);
                }
                mask[((size_t)b * PRE_K + i) * 16 + jw] = bits;
            }
        }
        sig(&semC[b], tid);
    }

    // ================= Fixpoint NMS + output (bg==0 only) =================
    if (bg == 0) {
        waitge(&semC[b], 16, tid);
        u64* Ksh  = (u64*)shm;                       // [2][16] ping-pong
        int* chgA = (int*)(shm + 256);               // 32 flags
        const u64* mb = mask + (size_t)b * PRE_K * 16;

        bool inr = tid < PRE_K;
        u64 key = inr ? cb[tid] : 0ull;
        bool valid = inr && ((u32)(key >> 32) != 0u);   // score>0.25 iff bits nonzero

        u64 low = (1ull << (tid & 63)) - 1ull;          // lane 0 -> 0

        // row i, pre-masked to j<i; only words k<=wv were written by IoU
        u64 rowm[16];
#pragma unroll
        for (int k = 0; k < 16; ++k) {
            u64 lt = (k < wv) ? ~0ull : ((k == wv) ? low : 0ull);
            u64 r = (inr && k <= wv) ? mb[(size_t)tid * 16 + k] : 0ull;
            rowm[k] = r & lt;
        }

        u64 v0 = __ballot(valid);                       // K^0 = valid
        if (lane == 0) Ksh[wv] = v0;
        if (tid < 32) chgA[tid] = 0;
        __syncthreads();

        int fin = 0;
        for (int it = 0; it < PRE_K + 2; ++it) {
            int p = it & 1;
            const u64* Kc = Ksh + p * 16;
            u64 kold = Kc[wv];
            u64 acc = 0;
#pragma unroll
            for (int k = 0; k < 16; ++k) acc |= rowm[k] & Kc[k];
            bool kept = valid && (acc == 0ull);
            u64 nk = __ballot(kept);
            if (lane == 0) {
                Ksh[(p ^ 1) * 16 + wv] = nk;
                if (nk != kold) chgA[it & 31] = 1;
            }
            __syncthreads();                            // one barrier per iteration
            fin = p ^ 1;
            if (chgA[it & 31] == 0) break;              // fixpoint certified
            if ((it & 31) == 31) {                      // recycle flag slots (rare)
                __syncthreads();
                if (tid < 32) chgA[tid] = 0;
                __syncthreads();
            }
        }
        const u64* Kf = Ksh + fin * 16;

        // epilogue: rank kept (by index) then zero-score backfill (by index)
        int pc = 0, Kt = 0;
#pragma unroll
        for (int k = 0; k < 16; ++k) {
            u64 kk = Kf[k];
            u64 lt = (k < wv) ? ~0ull : ((k == wv) ? low : 0ull);
            pc += __popcll(kk & lt);
            Kt += __popcll(kk);
        }
        if (inr) {
            bool kept = (Kf[wv] >> (tid & 63)) & 1ull;
            int row = kept ? pc : (Kt + (tid - pc));
            if (row < 100) {
                u32 a = ~(u32)key;
                float4 bx = boxes[(size_t)b * NA + a];
                int lab = labels[(size_t)b * NA + a];
                float fsc = kept ? __uint_as_float((u32)(key >> 32)) : 0.0f;
                float* dr = out + (size_t)(b * 100 + row) * 5;
                dr[0] = bx.x; dr[1] = bx.y; dr[2] = bx.z; dr[3] = bx.w; dr[4] = fsc;
                out[(size_t)NB * 100 * 5 + b * 100 + row] = (float)lab;
            }
        }
    }
}

extern "C" void kernel_launch(void* const* d_in, const int* in_sizes, int n_in,
                              void* d_out, int out_size, void* d_ws, size_t ws_size,
                              hipStream_t stream) {
    const float* cls0 = (const float*)d_in[0];
    const float* cls1 = (const float*)d_in[1];
    const float* cls2 = (const float*)d_in[2];
    const float* box0 = (const float*)d_in[3];
    const float* box1 = (const float*)d_in[4];
    const float* box2 = (const float*)d_in[5];
    float* out = (float*)d_out;

    char* w = (char*)d_ws;
    u64*    f_keys = (u64*)(w);
    float4* boxes  = (float4*)(w + 1075200);
    int*    labels = (int*)(w + 3225600);
    u64*    cand   = (u64*)(w + 3763200);
    u64*    mask   = (u64*)(w + 3894272);
    u32*    sem    = (u32*)(w + 5942272);

    // semaphores are 0xAA-poisoned before every launch -> zero them (captured)
    hipMemsetAsync(sem, 0, 256, stream);

    k_decode<<<dim3(17, NB), 256, 0, stream>>>(cls0, cls1, cls2, box0, box1, box2,
                                               f_keys, boxes, labels);
    k_post<<<256, 1024, 0, stream>>>(f_keys, boxes, labels, cand, mask, sem, out);
}

// Round 11
// 133.030 us; speedup vs baseline: 1.5530x; 1.0556x over previous
//
#include <hip/hip_runtime.h>
#include <math.h>
#include <stdint.h>

typedef unsigned long long u64;
typedef unsigned int u32;

#define NCLS 80
#define NA   8400
#define NB   16
#define PRE_K 1000

// ---------------- ws layout (bytes) ----------------
// f_keys : u64   [NB][NA]       @ 0         (1,075,200)
// boxes  : float4[NB][NA]       @ 1,075,200 (2,150,400)
// labels : int   [NB][NA]       @ 3,225,600 (  537,600)
// cand   : u64   [NB][1024]     @ 3,763,200 (  131,072)
// mask   : u64   [NB][1000][16] @ 3,894,272 (2,048,000)  lower-tri words only
// sem    : u32   [64]           @ 5,942,272 (256 B; zeroed by k_decode blk(0,0))
//          [0..15]=A flag (cand+sboxg ready), [16..31]=C cnt (mask ready)
// sboxg  : float4[NB][1024]     @ 5,942,528 (  262,144)  offset boxes of cand
// sarg   : float [NB][1024]     @ 6,204,672 (   65,536)  areas of cand

__device__ __forceinline__ void sig(u32* s, int tid) {
    __syncthreads();
    if (tid == 0) { __threadfence(); atomicAdd(s, 1u); }
}
__device__ __forceinline__ void waitge(u32* s, u32 target, int tid) {
    if (tid == 0) {
        while (__hip_atomic_load(s, __ATOMIC_RELAXED, __HIP_MEMORY_SCOPE_AGENT) < target)
            __builtin_amdgcn_s_sleep(8);
        __threadfence();
    }
    __syncthreads();
}

// ------------------------------------------------------------------
// Kernel 1: decode, float2 pairs, full thread utilization.
// grid (17, NB) x 256. Block (0,0) also zeros the semaphores (stream
// order makes them visible to k_post; replaces the memset dispatch).
// ------------------------------------------------------------------
__global__ __launch_bounds__(256) void k_decode(
    const float* __restrict__ cls0, const float* __restrict__ cls1,
    const float* __restrict__ cls2, const float* __restrict__ box0,
    const float* __restrict__ box1, const float* __restrict__ box2,
    u64* __restrict__ f_keys, float4* __restrict__ boxes,
    int* __restrict__ labels, u32* __restrict__ sem)
{
    if (blockIdx.x == 0 && blockIdx.y == 0 && threadIdx.x < 64)
        sem[threadIdx.x] = 0;

    int pa = blockIdx.x * 256 + threadIdx.x;     // pair index in batch
    int b  = blockIdx.y;
    if (pa >= 4200) return;

    const float *clsp, *boxp;
    int Wd, s, HW, hw;
    if (pa < 3200)      { clsp = cls0; boxp = box0; Wd = 80; s = 8;  HW = 6400; hw = 2 * pa; }
    else if (pa < 4000) { clsp = cls1; boxp = box1; Wd = 40; s = 16; HW = 1600; hw = 2 * pa - 6400; }
    else                { clsp = cls2; boxp = box2; Wd = 20; s = 32; HW = 400;  hw = 2 * pa - 8000; }
    int a = 2 * pa;

    const float* cp = clsp + (size_t)b * NCLS * HW + hw;
    float2 v = *(const float2*)cp;
    float m0 = v.x, m1 = v.y;
    int lab0 = 0, lab1 = 0;
#pragma unroll 8
    for (int c = 1; c < NCLS; ++c) {
        float2 vv = *(const float2*)(cp + (size_t)c * HW);
        if (vv.x > m0) { m0 = vv.x; lab0 = c; }   // strict > : first index on ties
        if (vv.y > m1) { m1 = vv.y; lab1 = c; }
    }
    double e0 = exp(-(double)m0), e1 = exp(-(double)m1);
    float sc0 = (float)(1.0 / (1.0 + e0));
    float sc1 = (float)(1.0 / (1.0 + e1));
    float sz0 = (sc0 > 0.25f) ? sc0 : 0.0f;
    float sz1 = (sc1 > 0.25f) ? sc1 : 0.0f;
    u64* fkp = f_keys + (size_t)b * NA + a;
    fkp[0] = ((u64)__float_as_uint(sz0) << 32) | (u64)(~(u32)a);
    fkp[1] = ((u64)__float_as_uint(sz1) << 32) | (u64)(~(u32)(a + 1));

    const float* bp = boxp + (size_t)b * 4 * HW + hw;
    float fs = (float)s;
    float2 q0 = *(const float2*)(bp);
    float2 q1 = *(const float2*)(bp + HW);
    float2 q2 = *(const float2*)(bp + 2 * HW);
    float2 q3 = *(const float2*)(bp + 3 * HW);
    float px = (float)((hw % Wd) * s);
    float py = (float)((hw / Wd) * s);
    float px1 = px + fs;                          // exact: small ints in float
    boxes[(size_t)b * NA + a]     = make_float4(px  - q0.x * fs, py - q1.x * fs, px  + q2.x * fs, py + q3.x * fs);
    boxes[(size_t)b * NA + a + 1] = make_float4(px1 - q0.y * fs, py - q1.y * fs, px1 + q2.y * fs, py + q3.y * fs);
    int2 lt; lt.x = lab0; lt.y = lab1;
    *(int2*)(labels + (size_t)b * NA + a) = lt;
}

// ------------------------------------------------------------------
// Kernel 2: per-batch pipeline, 16 blocks/batch, 2 handoffs.
//  bg==0: bucket-rank selection (O(Cv)) + publish offset boxes/areas
//  all  : IoU lower-tri chunk bg (division-free compare)
//  bg==0: fixpoint NMS + output
// R10 post-mortem: IoU fdiv ~10 VALU/pair = ~7.5us measured VALU; the
// compare inter/den>0.65 <=> inter>0.65*max(den,1e-6) removes it.
// ------------------------------------------------------------------
__global__ __launch_bounds__(1024, 1) void k_post(
    const u64* __restrict__ f_keys, const float4* __restrict__ boxes,
    const int* __restrict__ labels, u64* __restrict__ cand,
    u64* __restrict__ mask, u32* __restrict__ sem,
    float4* __restrict__ sboxg, float* __restrict__ sarg,
    float* __restrict__ out)
{
    __shared__ __align__(16) char shm[65536];
    __shared__ u32 wtot[16];
    __shared__ u32 s_total, s_B;
    int blk = blockIdx.x, tid = threadIdx.x, lane = tid & 63, wv = tid >> 6;
    int b = blk & 15, bg = blk >> 4;

    u32* semA = sem + 0;
    u32* semC = sem + 16;
    const u64* fk = f_keys + (size_t)b * NA;
    u64* cb = cand + (size_t)b * 1024;

    // ================= Selection (bg==0 only) =================
    if (bg == 0) {
        u32* R  = (u32*)shm;                 // 4096: histogram -> suffix counts
        u32* C  = (u32*)(shm + 16384);       // 4096: bucket-fill counters
        u64* BK = (u64*)(shm + 32768);       // 4096 bucket slots (32 KB)

        for (int i = tid; i < 4096; i += 1024) { R[i] = 0; C[i] = 0; }
        __syncthreads();

        // 1. histogram over score bits
        for (int i = tid; i < NA; i += 1024) {
            u32 sb = (u32)(fk[i] >> 32);
            if (sb) {
                int bin = (int)(sb >> 12) - 0x3E800;
                bin = max(0, min(bin, 4095));
                atomicAdd(&R[bin], 1u);
            }
        }
        __syncthreads();

        // 2. in-place suffix-sum: R[bin] = #keys in bins >= bin
        u32 h0 = R[4*tid], h1 = R[4*tid+1], h2 = R[4*tid+2], h3 = R[4*tid+3];
        u32 g = h0 + h1 + h2 + h3;
        u32 S = g;
#pragma unroll
        for (int off = 1; off < 64; off <<= 1) {
            u32 x = __shfl_down(S, off, 64);
            if (lane + off < 64) S += x;          // suffix-incl over lanes
        }
        if (lane == 0) wtot[wv] = S;
        __syncthreads();
        u32 wsuf = 0;
#pragma unroll
        for (int w = 0; w < 16; ++w) if (w > wv) wsuf += wtot[w];
        u32 above = (S - g) + wsuf;               // keys in bins > 4*tid+3
        u32 r3 = h3 + above, r2 = h2 + r3, r1 = h1 + r2, r0 = h0 + r1;
        R[4*tid] = r0; R[4*tid+1] = r1; R[4*tid+2] = r2; R[4*tid+3] = r3;
        if (tid == 0) s_total = 0;
        __syncthreads();
        if (tid == 0) s_total = R[0];
        __syncthreads();
        u32 total = s_total;

        // 3. threshold bin B (unique writer; B=0 if total<1000)
        if (tid == 0 && total < PRE_K) s_B = 0;
#pragma unroll
        for (int k = 0; k < 4; ++k) {
            int bin = 4*tid + k;
            u32 Rb = R[bin];
            u32 Rn = (bin < 4095) ? R[bin + 1] : 0;
            if (Rb >= PRE_K && Rn < PRE_K) s_B = (u32)bin;
        }
        __syncthreads();
        u32 B = s_B;
        u32 Cv = R[B];                            // survivors (bins >= B)

        if (Cv <= 4096) {
            // 4. bucket-place survivors at exact rank-base
            for (int i = tid; i < NA; i += 1024) {
                u64 key = fk[i];
                u32 sb = (u32)(key >> 32);
                if (sb) {
                    int bin = (int)(sb >> 12) - 0x3E800;
                    bin = max(0, min(bin, 4095));
                    if ((u32)bin >= B) {
                        u32 base = (bin < 4095) ? R[bin + 1] : 0;
                        u32 off = atomicAdd(&C[bin], 1u);
                        BK[base + off] = key;
                    }
                }
            }
            __syncthreads();
            // 5. exact rank = bucket base + #{same-bin keys greater}
            for (int s2 = tid; s2 < (int)Cv; s2 += 1024) {
                u64 key = BK[s2];
                u32 sb = (u32)(key >> 32);
                int bin = (int)(sb >> 12) - 0x3E800;
                bin = max(0, min(bin, 4095));
                u32 base = (bin < 4095) ? R[bin + 1] : 0;
                u32 n = R[bin] - base;
                u32 cnt = 0;
                for (u32 j = 0; j < n; ++j) cnt += (BK[base + j] > key) ? 1u : 0u;
                u32 rank = base + cnt;
                if (rank < PRE_K) cb[rank] = key;
            }
        } else {
            // fallback (pathological bin collisions): exact rank via global
            for (int i = tid; i < NA; i += 1024) {
                u64 key = fk[i];
                u32 sb = (u32)(key >> 32);
                if (!sb) continue;
                int bin = (int)(sb >> 12) - 0x3E800;
                bin = max(0, min(bin, 4095));
                if ((u32)bin < B) continue;
                u32 rank = 0;
                for (int j = 0; j < NA; ++j) rank += (fk[j] > key) ? 1u : 0u;
                if (rank < PRE_K) cb[rank] = key;
            }
        }
        // 6. zero-score backfill (reference: ties by index asc)
        for (int t2 = tid; (int)total + t2 < PRE_K; t2 += 1024)
            cb[total + t2] = (u64)(~(u32)t2);
        __syncthreads();

        // 7. publish offset boxes + areas once (IoU blocks consume coalesced)
        if (tid < PRE_K) {
            u64 key = cb[tid];
            u32 a = ~(u32)key;
            float4 bx = boxes[(size_t)b * NA + a];
            float off = (float)labels[(size_t)b * NA + a] * 8192.0f;  // exact mult
            float x1 = bx.x + off, y1 = bx.y + off, x2 = bx.z + off, y2 = bx.w + off;
            sboxg[(size_t)b * 1024 + tid] = make_float4(x1, y1, x2, y2);
            float w = fmaxf(__fsub_rn(x2, x1), 0.0f);
            float h = fmaxf(__fsub_rn(y2, y1), 0.0f);
            sarg[(size_t)b * 1024 + tid] = __fmul_rn(w, h);
        }
        __syncthreads();
        if (tid == 0) { __threadfence(); atomicExch(&semA[b], 1u); }
    }

    // ================= IoU lower-tri bitmask (chunk bg of batch b) =================
    {
        waitge(&semA[b], 1, tid);
        float4* sbox = (float4*)shm;                 // 1000 x 16 B
        float*  sar  = (float*)(shm + 16384);        // 1000 x 4 B

        if (tid < PRE_K) {
            sbox[tid] = sboxg[(size_t)b * 1024 + tid];
            sar[tid]  = sarg[(size_t)b * 1024 + tid];
        }
        __syncthreads();

        if (tid < 1008) {
            int jw = tid / 63, il = tid - jw * 63;
            int i = bg * 63 + il;
            if (i < PRE_K && jw <= (i >> 6)) {
                float4 A = sbox[i];
                float aar = sar[i];
                int jmax = min(64, PRE_K - jw * 64);
                if (jw == (i >> 6)) jmax = min(jmax, i & 63);  // only j<i bits used by NMS
                const float4* bj = sbox + jw * 64;
                const float*  aj = sar  + jw * 64;
                u64 bits = 0;
                for (int jj = 0; jj < jmax; ++jj) {
                    float4 Bx = bj[jj];                        // ds_read_b128 broadcast
                    float sab = aj[jj];
                    float lx = fmaxf(A.x, Bx.x), ly = fmaxf(A.y, Bx.y);
                    float rx = fminf(A.z, Bx.z), ry = fminf(A.w, Bx.w);
                    float ww = fmaxf(__fsub_rn(rx, lx), 0.0f);
                    float hh = fmaxf(__fsub_rn(ry, ly), 0.0f);
                    float inter = __fmul_rn(ww, hh);
                    float uni = __fsub_rn(__fadd_rn(aar, sab), inter);
                    // iou>0.65 <=> inter > 0.65*max(uni,1e-6)  (division-free)
                    if (inter > 0.65f * fmaxf(uni, 1e-6f)) bits |= (1ull << jj);
                }
                mask[((size_t)b * PRE_K + i) * 16 + jw] = bits;
            }
        }
        sig(&semC[b], tid);
    }

    // ================= Fixpoint NMS + output (bg==0 only) =================
    if (bg == 0) {
        waitge(&semC[b], 16, tid);
        u64* Ksh  = (u64*)shm;                       // [2][16] ping-pong
        int* chgA = (int*)(shm + 256);               // 32 flags
        const u64* mb = mask + (size_t)b * PRE_K * 16;

        bool inr = tid < PRE_K;
        u64 key = inr ? cb[tid] : 0ull;
        bool valid = inr && ((u32)(key >> 32) != 0u);   // score>0.25 iff bits nonzero

        u64 low = (1ull << (tid & 63)) - 1ull;          // lane 0 -> 0

        // row i, pre-masked to j<i; only words k<=wv were written by IoU
        u64 rowm[16];
#pragma unroll
        for (int k = 0; k < 16; ++k) {
            u64 lt = (k < wv) ? ~0ull : ((k == wv) ? low : 0ull);
            u64 r = (inr && k <= wv) ? mb[(size_t)tid * 16 + k] : 0ull;
            rowm[k] = r & lt;
        }

        u64 v0 = __ballot(valid);                       // K^0 = valid
        if (lane == 0) Ksh[wv] = v0;
        if (tid < 32) chgA[tid] = 0;
        __syncthreads();

        int fin = 0;
        for (int it = 0; it < PRE_K + 2; ++it) {
            int p = it & 1;
            const u64* Kc = Ksh + p * 16;
            u64 kold = Kc[wv];
            u64 acc = 0;
#pragma unroll
            for (int k = 0; k < 16; ++k) acc |= rowm[k] & Kc[k];
            bool kept = valid && (acc == 0ull);
            u64 nk = __ballot(kept);
            if (lane == 0) {
                Ksh[(p ^ 1) * 16 + wv] = nk;
                if (nk != kold) chgA[it & 31] = 1;
            }
            __syncthreads();                            // one barrier per iteration
            fin = p ^ 1;
            if (chgA[it & 31] == 0) break;              // fixpoint certified
            if ((it & 31) == 31) {                      // recycle flag slots (rare)
                __syncthreads();
                if (tid < 32) chgA[tid] = 0;
                __syncthreads();
            }
        }
        const u64* Kf = Ksh + fin * 16;

        // epilogue: rank kept (by index) then zero-score backfill (by index)
        int pc = 0, Kt = 0;
#pragma unroll
        for (int k = 0; k < 16; ++k) {
            u64 kk = Kf[k];
            u64 lt = (k < wv) ? ~0ull : ((k == wv) ? low : 0ull);
            pc += __popcll(kk & lt);
            Kt += __popcll(kk);
        }
        if (inr) {
            bool kept = (Kf[wv] >> (tid & 63)) & 1ull;
            int row = kept ? pc : (Kt + (tid - pc));
            if (row < 100) {
                u32 a = ~(u32)key;
                float4 bx = boxes[(size_t)b * NA + a];
                int lab = labels[(size_t)b * NA + a];
                float fsc = kept ? __uint_as_float((u32)(key >> 32)) : 0.0f;
                float* dr = out + (size_t)(b * 100 + row) * 5;
                dr[0] = bx.x; dr[1] = bx.y; dr[2] = bx.z; dr[3] = bx.w; dr[4] = fsc;
                out[(size_t)NB * 100 * 5 + b * 100 + row] = (float)lab;
            }
        }
    }
}

extern "C" void kernel_launch(void* const* d_in, const int* in_sizes, int n_in,
                              void* d_out, int out_size, void* d_ws, size_t ws_size,
                              hipStream_t stream) {
    const float* cls0 = (const float*)d_in[0];
    const float* cls1 = (const float*)d_in[1];
    const float* cls2 = (const float*)d_in[2];
    const float* box0 = (const float*)d_in[3];
    const float* box1 = (const float*)d_in[4];
    const float* box2 = (const float*)d_in[5];
    float* out = (float*)d_out;

    char* w = (char*)d_ws;
    u64*    f_keys = (u64*)(w);
    float4* boxes  = (float4*)(w + 1075200);
    int*    labels = (int*)(w + 3225600);
    u64*    cand   = (u64*)(w + 3763200);
    u64*    mask   = (u64*)(w + 3894272);
    u32*    sem    = (u32*)(w + 5942272);
    float4* sboxg  = (float4*)(w + 5942528);
    float*  sarg   = (float*)(w + 6204672);

    k_decode<<<dim3(17, NB), 256, 0, stream>>>(cls0, cls1, cls2, box0, box1, box2,
                                               f_keys, boxes, labels, sem);
    k_post<<<256, 1024, 0, stream>>>(f_keys, boxes, labels, cand, mask, sem,
                                     sboxg, sarg, out);
}